// Round 7
// baseline (364.590 us; speedup 1.0000x reference)
//
#include <hip/hip_runtime.h>
#include <math.h>

typedef short   s16x8  __attribute__((ext_vector_type(8)));
typedef __bf16  bf16x8 __attribute__((ext_vector_type(8)));
typedef float   f32x4  __attribute__((ext_vector_type(4)));

#define T_FREQ 169
#define NN     336      // L == n (output length)
#define CCH    512
#define BB     32
#define TP     176      // t padded to 11*16 (stage A M)
#define LP     352      // L padded to 11*32 (stage A K)
#define KP     192      // t padded to 6*32  (stage C K)
#define QK     128      // K per staged chunk in fallback cgemm

// ---- workspace layout (bytes), all offsets 16B-aligned ----
static constexpr size_t OFF_COEF = 0;                                  // 169 f32
static constexpr size_t OFF_FC   = 1024;                               // [176][352] bf16
static constexpr size_t OFF_FS   = OFF_FC + 124928;                    // [176][352] bf16
static constexpr size_t OFF_CCOS = OFF_FS + 124928;                    // [336][192] bf16
static constexpr size_t OFF_CSIN = OFF_CCOS + 130048;                  // [336][192] bf16
static constexpr size_t OFF_XT   = OFF_CSIN + 130048;                  // [32][512][352] bf16
static constexpr size_t OFF_XR   = OFF_XT + (size_t)BB*CCH*LP*2;       // [176][32][512] bf16
static constexpr size_t OFF_XI   = OFF_XR + (size_t)TP*BB*CCH*2;       // [176][32][512] bf16
static constexpr size_t OFF_YR   = OFF_XI + (size_t)TP*BB*CCH*2;       // [32][192][512] bf16
static constexpr size_t OFF_YI   = OFF_YR + (size_t)BB*KP*CCH*2;       // [32][192][512] bf16
static constexpr size_t OFF_WB   = OFF_YI + (size_t)BB*KP*CCH*2;       // [169][2][32][16][64][8] bf16 fragment-order
static constexpr size_t WB_BYTES = (size_t)T_FREQ*2*CCH*CCH*2;         // 177 MB
static constexpr size_t WS_NEED  = OFF_WB + WB_BYTES;

__device__ __forceinline__ unsigned short f2bf(float f){
  return __builtin_bit_cast(unsigned short, (__bf16)f);
}

__device__ __forceinline__ bf16x8 cvt8(float4 lo, float4 hi){
  bf16x8 r;
  r[0]=(__bf16)lo.x; r[1]=(__bf16)lo.y; r[2]=(__bf16)lo.z; r[3]=(__bf16)lo.w;
  r[4]=(__bf16)hi.x; r[5]=(__bf16)hi.y; r[6]=(__bf16)hi.z; r[7]=(__bf16)hi.w;
  return r;
}

__device__ __forceinline__ bf16x8 cvt8v(f32x4 lo, f32x4 hi){
  bf16x8 r;
  r[0]=(__bf16)lo[0]; r[1]=(__bf16)lo[1]; r[2]=(__bf16)lo[2]; r[3]=(__bf16)lo[3];
  r[4]=(__bf16)hi[0]; r[5]=(__bf16)hi[1]; r[6]=(__bf16)hi[2]; r[7]=(__bf16)hi[3];
  return r;
}

__device__ __forceinline__ f32x4 mfma16(bf16x8 a, bf16x8 b, f32x4 c){
  return __builtin_amdgcn_mfma_f32_16x16x32_bf16(a, b, c, 0, 0, 0);
}

typedef __attribute__((address_space(3))) unsigned lds_u32;
typedef __attribute__((address_space(1))) const unsigned g_u32;
__device__ __forceinline__ void gll16(const void* g, void* l){
  __builtin_amdgcn_global_load_lds((g_u32*)g, (lds_u32*)l, 16, 0, 0);
}

// ---------------- P1: coef softmax + twiddle tables ----------------
__global__ __launch_bounds__(256) void prep_tables(const float* __restrict__ wts, char* ws){
  float* coef = (float*)(ws + OFF_COEF);
  unsigned short* Fc  = (unsigned short*)(ws + OFF_FC);
  unsigned short* Fs  = (unsigned short*)(ws + OFF_FS);
  unsigned short* Cc  = (unsigned short*)(ws + OFF_CCOS);
  unsigned short* Cs  = (unsigned short*)(ws + OFF_CSIN);
  const float PI2_N = 6.283185307179586f / (float)NN;
  const float inv_sqrt_n = 0.05455447255899809f;  // 1/sqrt(336)

  if (blockIdx.x == 0){
    __shared__ float red[256];
    int tid = threadIdx.x;
    float v = (tid < T_FREQ) ? wts[tid] : -1e30f;
    red[tid] = v; __syncthreads();
    for (int s = 128; s > 0; s >>= 1){ if (tid < s) red[tid] = fmaxf(red[tid], red[tid+s]); __syncthreads(); }
    float mx = red[0]; __syncthreads();
    float e = (tid < T_FREQ) ? expf(v - mx) : 0.f;
    red[tid] = e; __syncthreads();
    for (int s = 128; s > 0; s >>= 1){ if (tid < s) red[tid] += red[tid+s]; __syncthreads(); }
    float ssum = red[0];
    if (tid < T_FREQ){
      float sc = (tid == 0 || tid == T_FREQ-1) ? 1.f : 2.f;
      coef[tid] = (e / ssum) * sc * inv_sqrt_n;
    }
    return;
  }
  int gid = (blockIdx.x - 1) * 256 + threadIdx.x;
  int stride = (gridDim.x - 1) * 256;
  for (int e = gid; e < TP*LP; e += stride){
    int i = e / LP, l = e % LP;
    float c = 0.f, s = 0.f;
    if (l < NN){
      int m = (i * l) % NN;
      float sv, cv; sincosf(PI2_N * (float)m, &sv, &cv);
      c = cv * inv_sqrt_n; s = -sv * inv_sqrt_n;
    }
    Fc[e] = f2bf(c); Fs[e] = f2bf(s);
  }
  for (int e = gid; e < NN*KP; e += stride){
    int l = e / KP, i = e % KP;
    float c = 0.f, s = 0.f;
    if (i < T_FREQ){
      int m = (i * l) % NN;
      float sv, cv; sincosf(PI2_N * (float)m, &sv, &cv);
      c = cv; s = -sv;
    }
    Cc[e] = f2bf(c); Cs[e] = f2bf(s);
  }
}

// ---------------- P2: x [b][l][c] f32 -> x_t [b][c][l] bf16 ----------------
__global__ __launch_bounds__(256) void transpose_x(const float* __restrict__ x, char* ws){
  unsigned short* xt = (unsigned short*)(ws + OFF_XT);
  __shared__ float tile[32][33];
  int bid = blockIdx.x;
  int b  = bid / (11*16);
  int rm = bid % (11*16);
  int lt = rm / 16, ct = rm % 16;
  int tx = threadIdx.x & 31, ty = threadIdx.x >> 5;   // 32 x 8
  #pragma unroll
  for (int k = 0; k < 4; ++k){
    int l = lt*32 + ty + k*8;
    int c = ct*32 + tx;
    float v = (l < NN) ? x[((size_t)b*NN + l)*CCH + c] : 0.f;
    tile[ty + k*8][tx] = v;
  }
  __syncthreads();
  #pragma unroll
  for (int k = 0; k < 4; ++k){
    int crow = ct*32 + ty + k*8;
    int lcol = lt*32 + tx;
    xt[((size_t)b*CCH + crow)*LP + lcol] = f2bf(tile[tx][ty + k*8]);
  }
}

// ---------------- Stage A: rfft as GEMM, M-split 2-way ----------------
__global__ __launch_bounds__(256) void stage_rfft(char* ws){
  const unsigned short* xt = (const unsigned short*)(ws + OFF_XT);
  const unsigned short* Fc = (const unsigned short*)(ws + OFF_FC);
  const unsigned short* Fs = (const unsigned short*)(ws + OFF_FS);
  unsigned short* xr = (unsigned short*)(ws + OFF_XR);
  unsigned short* xi = (unsigned short*)(ws + OFF_XI);

  int bid = blockIdx.x;
  int b  = bid >> 4;
  int rm = bid & 15;
  int c0 = (rm & 7) * 64;
  int mh = rm >> 3;
  int mbase = mh * 5;
  int tid = threadIdx.x, lane = tid & 63, wv = tid >> 6;
  int kg = lane >> 4, ln = lane & 15;
  int c = c0 + wv*16 + ln;

  f32x4 aR[6], aI[6];
  #pragma unroll
  for (int m = 0; m < 6; ++m){ aR[m] = (f32x4){0,0,0,0}; aI[m] = (f32x4){0,0,0,0}; }

  const unsigned short* xrow = xt + ((size_t)b*CCH + c)*LP;
  for (int kk = 0; kk < 11; ++kk){
    int ko = kk*32 + kg*8;
    bf16x8 bx = *(const bf16x8*)(xrow + ko);
    #pragma unroll
    for (int m = 0; m < 6; ++m){
      bf16x8 fc = *(const bf16x8*)(Fc + (size_t)((mbase+m)*16 + ln)*LP + ko);
      bf16x8 fs = *(const bf16x8*)(Fs + (size_t)((mbase+m)*16 + ln)*LP + ko);
      aR[m] = mfma16(fc, bx, aR[m]);
      aI[m] = mfma16(fs, bx, aI[m]);
    }
  }
  int rbase = kg*4;
  #pragma unroll
  for (int m = 0; m < 6; ++m){
    #pragma unroll
    for (int r = 0; r < 4; ++r){
      int i = (mbase+m)*16 + rbase + r;
      size_t off = ((size_t)i*BB + b)*CCH + c;
      xr[off] = f2bf(aR[m][r]);
      xi[off] = f2bf(aI[m][r]);
    }
  }
}

// ---------------- conv_w: m13-copy-shape W f32 -> bf16 fragment-order ----------------
// granule g = ((i*2+part)*512 + o)*64 + k8 ; reads 8 f32 (32B) coalesced per lane,
// writes one 16B bf16 granule at fragment-order address:
// wb[ ((( (i*2+part)*32 + o>>4 )*16 + k8>>2 )*64 + (k8&3)*16 + (o&15) ) * 8 ]
__global__ __launch_bounds__(256) void conv_w(const float* __restrict__ Wr, const float* __restrict__ Wi, char* ws){
  unsigned short* wb = (unsigned short*)(ws + OFF_WB);
  const size_t total = (size_t)T_FREQ*2*CCH*64;
  size_t stride = (size_t)gridDim.x * blockDim.x;
  for (size_t g = (size_t)blockIdx.x*blockDim.x + threadIdx.x; g < total; g += stride){
    unsigned k8   = (unsigned)(g & 63);
    unsigned o    = (unsigned)((g >> 6) & 511);
    unsigned pi   = (unsigned)(g >> 15);        // i*2 + part
    unsigned part = pi & 1;
    unsigned i    = pi >> 1;
    const float* src = (part ? Wi : Wr) + ((size_t)i*CCH + o)*CCH + k8*8;
    float4 lo = *(const float4*)(src);
    float4 hi = *(const float4*)(src + 4);
    size_t dst = ((((size_t)pi*32 + (o>>4))*16 + (k8>>2))*64 + ((k8&3)*16 + (o&15)))*8;
    *(bf16x8*)(wb + dst) = cvt8(lo, hi);
  }
}

// ---------------- cgemm_bf: m146-shape consumer, fragment-linear bf16 W ----------------
// Block = (freq i, 16-out tile ot). 4 waves: (mb, part). No LDS, no barriers.
// Per K-step: 2 wave-linear 1KB W loads + 2 L2-hot x loads + 2 MFMA.
__global__ __launch_bounds__(256, 6) void cgemm_bf(const float* __restrict__ br, const float* __restrict__ bi,
                                                   char* ws){
  const unsigned short* xr = (const unsigned short*)(ws + OFF_XR);
  const unsigned short* xi = (const unsigned short*)(ws + OFF_XI);
  const unsigned short* wb = (const unsigned short*)(ws + OFF_WB);
  const float* coef = (const float*)(ws + OFF_COEF);
  unsigned short* yr = (unsigned short*)(ws + OFF_YR);
  unsigned short* yi = (unsigned short*)(ws + OFF_YI);

  int bid = blockIdx.x;
  int i  = bid >> 5;
  int ot = bid & 31;
  int tid = threadIdx.x, lane = tid & 63, wv = tid >> 6;
  int kg = lane >> 4, ln = lane & 15;
  int mb = wv & 1, part = wv >> 1;

  const unsigned short* xa = xr + (size_t)(i*BB + mb*16 + ln)*CCH;
  const unsigned short* xb = xi + (size_t)(i*BB + mb*16 + ln)*CCH;
  const unsigned short* wrp = wb + ((((size_t)(i*2+0)*32 + ot)*16)*64 + lane)*8;
  const unsigned short* wip = wb + ((((size_t)(i*2+1)*32 + ot)*16)*64 + lane)*8;

  f32x4 acc = (f32x4){0,0,0,0};
  #pragma unroll
  for (int kk = 0; kk < 16; ++kk){
    int ko = kk*32 + kg*8;
    bf16x8 ar  = *(const bf16x8*)(xa + ko);
    bf16x8 ai  = *(const bf16x8*)(xb + ko);
    bf16x8 wr8 = *(const bf16x8*)(wrp + (size_t)kk*512);
    bf16x8 wi8 = *(const bf16x8*)(wip + (size_t)kk*512);
    bf16x8 nwi = __builtin_bit_cast(bf16x8, (s16x8)(__builtin_bit_cast(s16x8, wi8) ^ (short)0x8000));
    bf16x8 b1 = part ? wi8 : wr8;
    bf16x8 b2 = part ? wr8 : nwi;
    acc = mfma16(ar, b1, acc);     // part R: xr*Wr   | part I: xr*Wi
    acc = mfma16(ai, b2, acc);     // part R: -xi*Wi  | part I: xi*Wr
  }

  int o = ot*16 + ln;
  float cf = coef[i];
  float bias = (part ? bi : br)[(size_t)i*CCH + o];
  unsigned short* yp = part ? yi : yr;
  #pragma unroll
  for (int r = 0; r < 4; ++r){
    int bb = mb*16 + kg*4 + r;
    yp[((size_t)bb*KP + i)*CCH + o] = f2bf((acc[r] + bias) * cf);
  }
}

// ---------------- Fallback Stage B (v6): DMA-staged f32 (used only if ws too small) ----------------
#define WAIT_BAR(N) \
  asm volatile("s_waitcnt vmcnt(" #N ")" ::: "memory"); \
  __builtin_amdgcn_s_barrier(); \
  __builtin_amdgcn_sched_barrier(0)

#define COMPUTE_CHUNK(C) do{ \
  const float* wrr = &sW[C][0][ln][0]; \
  const float* wir = &sW[C][1][ln][0]; \
  _Pragma("unroll") \
  for (int kkl = 0; kkl < 4; ++kkl){ \
    int q0 = ((kkl*8 + kg*2 + 0) ^ ln7) << 2; \
    int q1 = ((kkl*8 + kg*2 + 1) ^ ln7) << 2; \
    f32x4 w0 = *(const f32x4*)(wrr + q0); \
    f32x4 w1 = *(const f32x4*)(wrr + q1); \
    f32x4 v0 = *(const f32x4*)(wir + q0); \
    f32x4 v1 = *(const f32x4*)(wir + q1); \
    bf16x8 wr8 = cvt8v(w0, w1); \
    bf16x8 wi8 = cvt8v(v0, v1); \
    bf16x8 nwi = __builtin_bit_cast(bf16x8, (s16x8)(__builtin_bit_cast(s16x8, wi8) ^ (short)0x8000)); \
    bf16x8 b1 = part ? wi8 : wr8; \
    bf16x8 b2 = part ? wr8 : nwi; \
    int ko = (C)*QK + kkl*32 + kg*8; \
    bf16x8 ar = *(const bf16x8*)(xa + ko); \
    bf16x8 ai = *(const bf16x8*)(xb + ko); \
    acc = mfma16(ar, b1, acc); \
    acc = mfma16(ai, b2, acc); \
  } \
}while(0)

__global__ __launch_bounds__(256, 2) void stage_cgemm(const float* __restrict__ Wr, const float* __restrict__ Wi,
                                                      const float* __restrict__ br, const float* __restrict__ bi,
                                                      char* ws){
  const unsigned short* xr = (const unsigned short*)(ws + OFF_XR);
  const unsigned short* xi = (const unsigned short*)(ws + OFF_XI);
  const float* coef = (const float*)(ws + OFF_COEF);
  unsigned short* yr = (unsigned short*)(ws + OFF_YR);
  unsigned short* yi = (unsigned short*)(ws + OFF_YI);

  __shared__ float sW[4][2][16][QK];

  int bid = blockIdx.x;
  int i  = bid >> 5;
  int ot = bid & 31;
  int tid = threadIdx.x, lane = tid & 63, wv = tid >> 6;
  int kg = lane >> 4, ln = lane & 15, ln7 = ln & 7;
  int mb = wv & 1, part = wv >> 1;

  const unsigned short* xa = xr + (size_t)(i*BB + mb*16 + ln)*CCH;
  const unsigned short* xb = xi + (size_t)(i*BB + mb*16 + ln)*CCH;

  {
    const float* wbase = (wv >> 1) ? Wi : Wr;
    const float* gW = wbase + ((size_t)i*CCH + ot*16)*CCH;
    int rl = lane >> 5, g = lane & 31;
    #pragma unroll
    for (int c = 0; c < 4; ++c){
      #pragma unroll
      for (int j = 0; j < 4; ++j){
        int rb = (wv & 1)*8 + j*2;
        int r  = rb + rl;
        int G  = g ^ (r & 7);
        gll16(gW + (size_t)r*CCH + c*QK + G*4, &sW[c][wv>>1][rb][0]);
      }
      __builtin_amdgcn_sched_barrier(0);
    }
  }

  f32x4 acc = (f32x4){0,0,0,0};

  WAIT_BAR(12); COMPUTE_CHUNK(0);
  WAIT_BAR(8);  COMPUTE_CHUNK(1);
  WAIT_BAR(4);  COMPUTE_CHUNK(2);
  WAIT_BAR(0);  COMPUTE_CHUNK(3);

  int o = ot*16 + ln;
  float cf = coef[i];
  float bias = (part ? bi : br)[(size_t)i*CCH + o];
  unsigned short* yp = part ? yi : yr;
  #pragma unroll
  for (int r = 0; r < 4; ++r){
    int bb = mb*16 + kg*4 + r;
    yp[((size_t)bb*KP + i)*CCH + o] = f2bf((acc[r] + bias) * cf);
  }
}

// ---------------- Stage C: irfft projection, M-split 2-way ----------------
__global__ __launch_bounds__(256) void stage_irfft(const char* ws_c, float* __restrict__ out){
  const char* ws = ws_c;
  const unsigned short* Cc = (const unsigned short*)(ws + OFF_CCOS);
  const unsigned short* Cs = (const unsigned short*)(ws + OFF_CSIN);
  const unsigned short* yr = (const unsigned short*)(ws + OFF_YR);
  const unsigned short* yi = (const unsigned short*)(ws + OFF_YI);

  __shared__ unsigned short lr[64][40];
  __shared__ unsigned short li[64][40];

  int bid = blockIdx.x;
  int b  = bid >> 4;
  int rm = bid & 15;
  int c0 = (rm & 7) * 64;
  int mh = rm >> 3;
  int mbase = mh * 10;
  int tid = threadIdx.x, lane = tid & 63, wv = tid >> 6;
  int kg = lane >> 4, ln = lane & 15;

  f32x4 acc[11];
  #pragma unroll
  for (int m = 0; m < 11; ++m) acc[m] = (f32x4){0,0,0,0};

  for (int kk = 0; kk < 6; ++kk){
    if (kk) __syncthreads();
    #pragma unroll
    for (int q = 0; q < 8; ++q){
      int idx = q*256 + tid;
      int ir = idx >> 6, cc = idx & 63;
      int i = kk*32 + ir;
      unsigned short vr = 0, vi = 0;
      if (i < T_FREQ){
        size_t off = ((size_t)b*KP + i)*CCH + c0 + cc;
        vr = yr[off]; vi = yi[off];
      }
      lr[cc][ir] = vr;
      li[cc][ir] = vi;
    }
    __syncthreads();
    int ko = kk*32 + kg*8;
    bf16x8 blr = *(const bf16x8*)(&lr[wv*16 + ln][kg*8]);
    bf16x8 bli = *(const bf16x8*)(&li[wv*16 + ln][kg*8]);
    #pragma unroll
    for (int m = 0; m < 11; ++m){
      bf16x8 ac = *(const bf16x8*)(Cc + (size_t)((mbase+m)*16 + ln)*KP + ko);
      bf16x8 as = *(const bf16x8*)(Cs + (size_t)((mbase+m)*16 + ln)*KP + ko);
      acc[m] = mfma16(ac, blr, acc[m]);
      acc[m] = mfma16(as, bli, acc[m]);
    }
  }

  int cdst = c0 + wv*16 + ln;
  #pragma unroll
  for (int m = 0; m < 11; ++m){
    #pragma unroll
    for (int r = 0; r < 4; ++r){
      int l = (mbase+m)*16 + kg*4 + r;
      out[((size_t)b*NN + l)*CCH + cdst] = acc[m][r];
    }
  }
}

extern "C" void kernel_launch(void* const* d_in, const int* in_sizes, int n_in,
                              void* d_out, int out_size, void* d_ws, size_t ws_size,
                              hipStream_t stream){
  const float* x   = (const float*)d_in[0];
  const float* Wr  = (const float*)d_in[1];
  const float* Wi  = (const float*)d_in[2];
  const float* br  = (const float*)d_in[3];
  const float* bi  = (const float*)d_in[4];
  const float* wts = (const float*)d_in[5];
  char* ws = (char*)d_ws;

  const bool two_pass = (ws_size >= WS_NEED);

  if (two_pass){
    conv_w<<<2048, 256, 0, stream>>>(Wr, Wi, ws);
  }
  prep_tables<<<257, 256, 0, stream>>>(wts, ws);
  transpose_x<<<32*11*16, 256, 0, stream>>>(x, ws);
  stage_rfft<<<512, 256, 0, stream>>>(ws);
  if (two_pass){
    cgemm_bf<<<T_FREQ*32, 256, 0, stream>>>(br, bi, ws);
  } else {
    stage_cgemm<<<T_FREQ*32, 256, 0, stream>>>(Wr, Wi, br, bi, ws);
  }
  stage_irfft<<<512, 256, 0, stream>>>(ws, (float*)d_out);
}

// Round 9
// 188.765 us; speedup vs baseline: 1.9314x; 1.9314x over previous
//
#include <hip/hip_runtime.h>
#include <math.h>

typedef short   s16x8  __attribute__((ext_vector_type(8)));
typedef __bf16  bf16x8 __attribute__((ext_vector_type(8)));
typedef float   f32x4  __attribute__((ext_vector_type(4)));

#define T_FREQ 169
#define NN     336      // L == n (output length)
#define CCH    512
#define BB     32
#define TP     176      // t padded to 11*16 (stage A M)
#define LP     352      // L padded to 11*32 (stage A K)
#define KP     192      // t padded to 6*32  (stage C K)
#define NT_I   75       // i >= NT_I -> non-temporal W loads (keep first ~150 MB L3-resident)

// ---- workspace layout (bytes), all offsets 16B-aligned ----
static constexpr size_t OFF_COEF = 0;                                  // 169 f32
static constexpr size_t OFF_FC   = 1024;                               // [176][352] bf16 (cos/sqrt(n))
static constexpr size_t OFF_FS   = OFF_FC + 124928;                    // [176][352] bf16 (-sin/sqrt(n))
static constexpr size_t OFF_CCOS = OFF_FS + 124928;                    // [336][192] bf16 cos
static constexpr size_t OFF_CSIN = OFF_CCOS + 130048;                  // [336][192] bf16 -sin
static constexpr size_t OFF_XT   = OFF_CSIN + 130048;                  // [32][512][352] bf16 (x transposed)
static constexpr size_t OFF_XR   = OFF_XT + (size_t)BB*CCH*LP*2;       // [176][32][512] bf16
static constexpr size_t OFF_XI   = OFF_XR + (size_t)TP*BB*CCH*2;       // [176][32][512] bf16
static constexpr size_t OFF_Y    = OFF_XI + (size_t)TP*BB*CCH*2;       // [32][192][512] (bf16 r, bf16 i) packed u32

__device__ __forceinline__ unsigned short f2bf(float f){
  unsigned u = __builtin_bit_cast(unsigned, f);
  u = (u + 0x7fffu + ((u >> 16) & 1u)) >> 16;   // round-to-nearest-even
  return (unsigned short)u;
}

__device__ __forceinline__ f32x4 mfma16(bf16x8 a, bf16x8 b, f32x4 c){
  return __builtin_amdgcn_mfma_f32_16x16x32_bf16(a, b, c, 0, 0, 0);
}

// W load with optional non-temporal hint (wave-uniform flag).
// NOTE: __builtin_nontemporal_load requires scalar/ext-vector types -> use f32x4.
__device__ __forceinline__ f32x4 ldW(const float* p, bool nt){
  if (nt) return __builtin_nontemporal_load((const f32x4*)p);
  return *(const f32x4*)p;
}

// ---------------- P1: coef softmax + twiddle tables ----------------
__global__ __launch_bounds__(256) void prep_tables(const float* __restrict__ wts, char* ws){
  float* coef = (float*)(ws + OFF_COEF);
  unsigned short* Fc  = (unsigned short*)(ws + OFF_FC);
  unsigned short* Fs  = (unsigned short*)(ws + OFF_FS);
  unsigned short* Cc  = (unsigned short*)(ws + OFF_CCOS);
  unsigned short* Cs  = (unsigned short*)(ws + OFF_CSIN);
  const float PI2_N = 6.283185307179586f / (float)NN;
  const float inv_sqrt_n = 0.05455447255899809f;  // 1/sqrt(336)

  if (blockIdx.x == 0){
    __shared__ float red[256];
    int tid = threadIdx.x;
    float v = (tid < T_FREQ) ? wts[tid] : -1e30f;
    red[tid] = v; __syncthreads();
    for (int s = 128; s > 0; s >>= 1){ if (tid < s) red[tid] = fmaxf(red[tid], red[tid+s]); __syncthreads(); }
    float mx = red[0]; __syncthreads();
    float e = (tid < T_FREQ) ? expf(v - mx) : 0.f;
    red[tid] = e; __syncthreads();
    for (int s = 128; s > 0; s >>= 1){ if (tid < s) red[tid] += red[tid+s]; __syncthreads(); }
    float ssum = red[0];
    if (tid < T_FREQ){
      float sc = (tid == 0 || tid == T_FREQ-1) ? 1.f : 2.f;
      coef[tid] = (e / ssum) * sc * inv_sqrt_n;
    }
    return;
  }
  int gid = (blockIdx.x - 1) * 256 + threadIdx.x;
  int stride = (gridDim.x - 1) * 256;
  // forward DFT matrices [TP][LP]: Fc = cos(th)/sqrt(n), Fs = -sin(th)/sqrt(n)
  for (int e = gid; e < TP*LP; e += stride){
    int i = e / LP, l = e % LP;
    float c = 0.f, s = 0.f;
    if (l < NN){
      int m = (i * l) % NN;
      float sv, cv; sincosf(PI2_N * (float)m, &sv, &cv);
      c = cv * inv_sqrt_n; s = -sv * inv_sqrt_n;
    }
    Fc[e] = f2bf(c); Fs[e] = f2bf(s);
  }
  // inverse projection matrices [NN][KP]: Cc = cos, Cs = -sin (zero-padded i>=169)
  for (int e = gid; e < NN*KP; e += stride){
    int l = e / KP, i = e % KP;
    float c = 0.f, s = 0.f;
    if (i < T_FREQ){
      int m = (i * l) % NN;
      float sv, cv; sincosf(PI2_N * (float)m, &sv, &cv);
      c = cv; s = -sv;
    }
    Cc[e] = f2bf(c); Cs[e] = f2bf(s);
  }
}

// ---------------- P2: x [b][l][c] f32 -> x_t [b][c][l] bf16 (l zero-padded to 352) ----------------
__global__ __launch_bounds__(256) void transpose_x(const float* __restrict__ x, char* ws){
  unsigned short* xt = (unsigned short*)(ws + OFF_XT);
  __shared__ float tile[32][33];
  int bid = blockIdx.x;
  int b  = bid / (11*16);
  int rm = bid % (11*16);
  int lt = rm / 16, ct = rm % 16;
  int tx = threadIdx.x & 31, ty = threadIdx.x >> 5;   // 32 x 8
  #pragma unroll
  for (int k = 0; k < 4; ++k){
    int l = lt*32 + ty + k*8;
    int c = ct*32 + tx;
    float v = (l < NN) ? x[((size_t)b*NN + l)*CCH + c] : 0.f;
    tile[ty + k*8][tx] = v;
  }
  __syncthreads();
  #pragma unroll
  for (int k = 0; k < 4; ++k){
    int crow = ct*32 + ty + k*8;
    int lcol = lt*32 + tx;
    xt[((size_t)b*CCH + crow)*LP + lcol] = f2bf(tile[tx][ty + k*8]);
  }
}

// ---------------- Stage A: rfft as GEMM. Xr/Xi[i][b][c] = sum_l F[i][l] * x_t[b][c][l] ----------------
__global__ __launch_bounds__(256) void stage_rfft(char* ws){
  const unsigned short* xt = (const unsigned short*)(ws + OFF_XT);
  const unsigned short* Fc = (const unsigned short*)(ws + OFF_FC);
  const unsigned short* Fs = (const unsigned short*)(ws + OFF_FS);
  unsigned short* xr = (unsigned short*)(ws + OFF_XR);
  unsigned short* xi = (unsigned short*)(ws + OFF_XI);

  int b  = blockIdx.x >> 3;
  int c0 = (blockIdx.x & 7) * 64;
  int tid = threadIdx.x, lane = tid & 63, wv = tid >> 6;
  int kg = lane >> 4, ln = lane & 15;
  int c = c0 + wv*16 + ln;

  f32x4 aR[11], aI[11];
  #pragma unroll
  for (int m = 0; m < 11; ++m){ aR[m] = (f32x4){0,0,0,0}; aI[m] = (f32x4){0,0,0,0}; }

  const unsigned short* xrow = xt + ((size_t)b*CCH + c)*LP;
  for (int kk = 0; kk < 11; ++kk){
    int ko = kk*32 + kg*8;
    bf16x8 bx = *(const bf16x8*)(xrow + ko);
    #pragma unroll
    for (int m = 0; m < 11; ++m){
      bf16x8 fc = *(const bf16x8*)(Fc + (size_t)(m*16 + ln)*LP + ko);
      bf16x8 fs = *(const bf16x8*)(Fs + (size_t)(m*16 + ln)*LP + ko);
      aR[m] = mfma16(fc, bx, aR[m]);
      aI[m] = mfma16(fs, bx, aI[m]);
    }
  }
  int rbase = kg*4;
  #pragma unroll
  for (int m = 0; m < 11; ++m){
    #pragma unroll
    for (int r = 0; r < 4; ++r){
      int i = m*16 + rbase + r;
      size_t off = ((size_t)i*BB + b)*CCH + c;
      xr[off] = f2bf(aR[m][r]);
      xi[off] = f2bf(aI[m][r]);
    }
  }
}

// ---------------- Stage B: per-frequency complex GEMM (r0/r1 structure, 125us measured) ----------------
// + L3 residency partition: W loads for i >= NT_I are non-temporal so the first
//   ~150 MB of W stays Infinity-Cache-resident across graph replays.
__global__ __launch_bounds__(256) void stage_cgemm(const float* __restrict__ Wr, const float* __restrict__ Wi,
                                                   const float* __restrict__ br, const float* __restrict__ bi,
                                                   char* ws){
  const unsigned short* xr = (const unsigned short*)(ws + OFF_XR);
  const unsigned short* xi = (const unsigned short*)(ws + OFF_XI);
  const float* coef = (const float*)(ws + OFF_COEF);
  unsigned int* y = (unsigned int*)(ws + OFF_Y);

  int i  = blockIdx.x >> 2;
  int nb = blockIdx.x & 3;
  int tid = threadIdx.x, lane = tid & 63, wv = tid >> 6;
  int kg = lane >> 4, ln = lane & 15;
  int o0 = nb*128 + wv*32;
  const bool useNT = (i >= NT_I);

  f32x4 accR[2][2], accI[2][2];
  #pragma unroll
  for (int m = 0; m < 2; ++m)
    #pragma unroll
    for (int n = 0; n < 2; ++n){ accR[m][n] = (f32x4){0,0,0,0}; accI[m][n] = (f32x4){0,0,0,0}; }

  const size_t wbase = (size_t)i * CCH * CCH;
  const size_t xbase = (size_t)i * BB * CCH;

  for (int kk = 0; kk < 16; ++kk){
    int ko = kk*32 + kg*8;
    bf16x8 ar[2], ai[2];
    #pragma unroll
    for (int mb = 0; mb < 2; ++mb){
      ar[mb] = *(const bf16x8*)(xr + xbase + (size_t)(mb*16 + ln)*CCH + ko);
      ai[mb] = *(const bf16x8*)(xi + xbase + (size_t)(mb*16 + ln)*CCH + ko);
    }
    #pragma unroll
    for (int nt = 0; nt < 2; ++nt){
      const float* wrp = Wr + wbase + (size_t)(o0 + nt*16 + ln)*CCH + ko;
      const float* wip = Wi + wbase + (size_t)(o0 + nt*16 + ln)*CCH + ko;
      f32x4 r0 = ldW(wrp, useNT);
      f32x4 r1 = ldW(wrp + 4, useNT);
      f32x4 i0 = ldW(wip, useNT);
      f32x4 i1 = ldW(wip + 4, useNT);
      s16x8 tr, ti;
      tr[0]=f2bf(r0[0]); tr[1]=f2bf(r0[1]); tr[2]=f2bf(r0[2]); tr[3]=f2bf(r0[3]);
      tr[4]=f2bf(r1[0]); tr[5]=f2bf(r1[1]); tr[6]=f2bf(r1[2]); tr[7]=f2bf(r1[3]);
      ti[0]=f2bf(i0[0]); ti[1]=f2bf(i0[1]); ti[2]=f2bf(i0[2]); ti[3]=f2bf(i0[3]);
      ti[4]=f2bf(i1[0]); ti[5]=f2bf(i1[1]); ti[6]=f2bf(i1[2]); ti[7]=f2bf(i1[3]);
      s16x8 tin = ti ^ (short)0x8000;              // -Wi
      bf16x8 bwr  = __builtin_bit_cast(bf16x8, tr);
      bf16x8 bwi  = __builtin_bit_cast(bf16x8, ti);
      bf16x8 bwin = __builtin_bit_cast(bf16x8, tin);
      #pragma unroll
      for (int mb = 0; mb < 2; ++mb){
        accR[mb][nt] = mfma16(ar[mb], bwr,  accR[mb][nt]);  // xr*Wr
        accR[mb][nt] = mfma16(ai[mb], bwin, accR[mb][nt]);  // -xi*Wi
        accI[mb][nt] = mfma16(ar[mb], bwi,  accI[mb][nt]);  // xr*Wi
        accI[mb][nt] = mfma16(ai[mb], bwr,  accI[mb][nt]);  // xi*Wr
      }
    }
  }

  float cf = coef[i];
  #pragma unroll
  for (int nt = 0; nt < 2; ++nt){
    int o = o0 + nt*16 + ln;
    float fbr = br[(size_t)i*CCH + o];
    float fbi = bi[(size_t)i*CCH + o];
    #pragma unroll
    for (int mb = 0; mb < 2; ++mb){
      #pragma unroll
      for (int r = 0; r < 4; ++r){
        float vr = (accR[mb][nt][r] + fbr) * cf;
        float vi = (accI[mb][nt][r] + fbi) * cf;
        int bb = mb*16 + kg*4 + r;
        y[((size_t)bb*KP + i)*CCH + o] = (unsigned)f2bf(vr) | ((unsigned)f2bf(vi) << 16);
      }
    }
  }
}

// ---------------- Stage C: out[b][l][c] = sum_i Cc[l][i]*yr[i][c] + Cs[l][i]*yi[i][c] ----------------
__global__ __launch_bounds__(256) void stage_irfft(const char* ws_c, float* __restrict__ out){
  const char* ws = ws_c;
  const unsigned short* Cc = (const unsigned short*)(ws + OFF_CCOS);
  const unsigned short* Cs = (const unsigned short*)(ws + OFF_CSIN);
  const unsigned int* y = (const unsigned int*)(ws + OFF_Y);

  __shared__ unsigned short lr[64][40];   // [c][i] transposed tile, 16B-aligned rows
  __shared__ unsigned short li[64][40];

  int b  = blockIdx.x >> 3;
  int c0 = (blockIdx.x & 7) * 64;
  int tid = threadIdx.x, lane = tid & 63, wv = tid >> 6;
  int kg = lane >> 4, ln = lane & 15;

  f32x4 acc[21];
  #pragma unroll
  for (int m = 0; m < 21; ++m) acc[m] = (f32x4){0,0,0,0};

  for (int kk = 0; kk < 6; ++kk){
    if (kk) __syncthreads();
    #pragma unroll
    for (int q = 0; q < 8; ++q){
      int idx = q*256 + tid;
      int ir = idx >> 6, cc = idx & 63;
      int i = kk*32 + ir;
      unsigned u = (i < T_FREQ) ? y[((size_t)b*KP + i)*CCH + c0 + cc] : 0u;
      lr[cc][ir] = (unsigned short)(u & 0xffffu);
      li[cc][ir] = (unsigned short)(u >> 16);
    }
    __syncthreads();
    int ko = kk*32 + kg*8;
    bf16x8 blr = *(const bf16x8*)(&lr[wv*16 + ln][kg*8]);
    bf16x8 bli = *(const bf16x8*)(&li[wv*16 + ln][kg*8]);
    #pragma unroll
    for (int m = 0; m < 21; ++m){
      bf16x8 ac = *(const bf16x8*)(Cc + (size_t)(m*16 + ln)*KP + ko);
      bf16x8 as = *(const bf16x8*)(Cs + (size_t)(m*16 + ln)*KP + ko);
      acc[m] = mfma16(ac, blr, acc[m]);
      acc[m] = mfma16(as, bli, acc[m]);
    }
  }

  int cdst = c0 + wv*16 + ln;
  #pragma unroll
  for (int m = 0; m < 21; ++m){
    #pragma unroll
    for (int r = 0; r < 4; ++r){
      int l = m*16 + kg*4 + r;
      out[((size_t)b*NN + l)*CCH + cdst] = acc[m][r];
    }
  }
}

extern "C" void kernel_launch(void* const* d_in, const int* in_sizes, int n_in,
                              void* d_out, int out_size, void* d_ws, size_t ws_size,
                              hipStream_t stream){
  const float* x   = (const float*)d_in[0];
  const float* Wr  = (const float*)d_in[1];
  const float* Wi  = (const float*)d_in[2];
  const float* br  = (const float*)d_in[3];
  const float* bi  = (const float*)d_in[4];
  const float* wts = (const float*)d_in[5];
  char* ws = (char*)d_ws;

  prep_tables<<<257, 256, 0, stream>>>(wts, ws);
  transpose_x<<<32*11*16, 256, 0, stream>>>(x, ws);
  stage_rfft<<<256, 256, 0, stream>>>(ws);
  stage_cgemm<<<T_FREQ*4, 256, 0, stream>>>(Wr, Wi, br, bi, ws);
  stage_irfft<<<256, 256, 0, stream>>>(ws, (float*)d_out);
}